// Round 9
// baseline (47.750 us; speedup 1.0000x reference)
//
#include <hip/hip_runtime.h>
#include <cstdint>
#include <cstddef>

// Problem constants
#define B_ 256
#define D_ 512
#define P_ 128
#define E_ 128

typedef unsigned short u16;
typedef unsigned int   u32;
typedef __bf16  bf16x8_t __attribute__((ext_vector_type(8)));
typedef float   f32x4_t  __attribute__((ext_vector_type(4)));
typedef u16     u16x4_t  __attribute__((ext_vector_type(4)));
typedef u16     u16x8_t  __attribute__((ext_vector_type(8)));

__device__ __forceinline__ u16 f2bf(float f) {
  union { float f; unsigned int u; } c; c.f = f;
  unsigned int u = c.u;
  unsigned int r = (u + 0x7FFFu + ((u >> 16) & 1u)) >> 16;
  return (u16)r;
}
__device__ __forceinline__ float bf2f(u16 v) {
  union { unsigned int u; float f; } c; c.u = (unsigned int)v << 16;
  return c.f;
}

// ---------------------------------------------------------------------------
// Pass 1 (merged): transpose + convert BOTH x and W, f32 -> bf16.
// Block o<256: x [b][512 d][128 p] -> xT[p][b][d]
// Block o>=256: W [p][512 d][128 e] -> Wt[p][e][d]
// Both are [outer][R=512][C=128] f32 -> dst(c,outer,r).
// ---------------------------------------------------------------------------
__global__ __launch_bounds__(256) void transpose_both_kernel(
    const float* __restrict__ x, const float* __restrict__ W,
    u16* __restrict__ xT, u16* __restrict__ Wt) {
  __shared__ float tile[64][65];

  const int ob = blockIdx.x;
  const bool isX = (ob < B_);
  const int o = isX ? ob : (ob - B_);
  const float* src = isX ? x : W;
  u16* dst = isX ? xT : Wt;
  const size_t rs = isX ? (size_t)B_ * D_ : (size_t)D_;        // dst row stride (c)
  const size_t os = isX ? (size_t)D_ : (size_t)E_ * D_;        // dst outer stride

  const int r0 = blockIdx.y * 64;     // d block
  const int c0 = blockIdx.z * 64;     // p/e block
  const int t  = threadIdx.x;

  const float* s = src + (size_t)o * D_ * 128 + (size_t)r0 * 128 + c0;

  {
    const int lr = t >> 4;
    const int lc = (t & 15) * 4;
    #pragma unroll
    for (int it = 0; it < 4; ++it) {
      const int r = lr + it * 16;
      const float4 v = *reinterpret_cast<const float4*>(s + (size_t)r * 128 + lc);
      tile[r][lc + 0] = v.x; tile[r][lc + 1] = v.y;
      tile[r][lc + 2] = v.z; tile[r][lc + 3] = v.w;
    }
  }
  __syncthreads();

  {
    const int wc = t >> 3;
    const int wd = (t & 7) * 8;
    #pragma unroll
    for (int it = 0; it < 2; ++it) {
      const int c = wc + it * 32;
      u16x8_t pkv;
      #pragma unroll
      for (int j = 0; j < 8; ++j) pkv[j] = f2bf(tile[wd + j][c]);
      *reinterpret_cast<u16x8_t*>(dst + (size_t)(c0 + c) * rs +
                                  (size_t)o * os + r0 + wd) = pkv;
    }
  }
}

// ---------------------------------------------------------------------------
// Pass 2: per-p bf16 TN GEMM, all-bf16 global_load_lds staging, 64x64xBK64,
// 4 waves, 8 K-steps, TRIPLE-buffered LDS, depth-3 counted-vmcnt pipeline:
//   iter k: ds_read buf[k%3] -> lgkmcnt(0) -> barrier (all reads done)
//           -> stage tile k+3 into buf[k%3] (4x global_load_lds)
//           -> 8 MFMA -> vmcnt(8) (tile k+1 landed; k+2,k+3 in flight) -> bar
// Prefetch window ~2 iterations (~600cy) covers L2/L3 latency.
// Grid = 128p x 4bt x 2et = 1024 WGs, 3 WG/CU (48KB LDS), XCD-swizzled p.
// Epilogue: coalesced bf16 store to ws2[p][b][e] (+bias).
// ---------------------------------------------------------------------------

// swizzled elem index of 16B chunk g (0..7) in row `row` of a [64]x[64]-u16 tile
#define SWZ_ELEM(row, g) (((row) << 6) + ((((g) ^ ((row) & 7))) << 3))

__global__ __launch_bounds__(256, 3) void gemm_kernel(
    const u16* __restrict__ xT, const u16* __restrict__ Wt,
    const float* __restrict__ bias, u16* __restrict__ ws2) {
  __shared__ __attribute__((aligned(16))) u16 As[3][64 * 64];
  __shared__ __attribute__((aligned(16))) u16 Bs[3][64 * 64];

  const int wg   = blockIdx.x;
  const int xcd  = wg & 7;
  const int i    = wg >> 3;            // 0..127
  const int p    = xcd * 16 + (i & 15);
  const int tile = i >> 4;             // 0..7
  const int b0   = (tile & 3) * 64;
  const int e0t  = (tile >> 2) * 64;

  const int t    = threadIdx.x;
  const int lane = t & 63;
  const int wv   = t >> 6;
  const int wr   = wv >> 1;            // wave row (b half)
  const int wc   = wv & 1;             // wave col (e half)

  const u16* Ag = xT + (size_t)p * (B_ * D_) + (size_t)b0 * D_;
  const u16* Bg = Wt + ((size_t)p * E_ + e0t) * D_;

  // staging: thread t stages 16B chunks t and t+256; LDS dest linear,
  // global source chunk pre-XOR-swizzled within its 128B row (rule #21).
  const int r1 = t >> 3;
  const int sw = (((t & 7) ^ (r1 & 7)) << 3);

  const int fr = lane & 15;
  const int fq = lane >> 4;

  f32x4_t acc[2][2] = {};

#define STAGE_AB(buf, d0) do { \
    __builtin_amdgcn_global_load_lds( \
        (const __attribute__((address_space(1))) void*)(Ag + (size_t)r1 * D_ + (d0) + sw), \
        (__attribute__((address_space(3))) void*)&As[buf][wv * 512], 16, 0, 0); \
    __builtin_amdgcn_global_load_lds( \
        (const __attribute__((address_space(1))) void*)(Ag + (size_t)(r1 + 32) * D_ + (d0) + sw), \
        (__attribute__((address_space(3))) void*)&As[buf][2048 + wv * 512], 16, 0, 0); \
    __builtin_amdgcn_global_load_lds( \
        (const __attribute__((address_space(1))) void*)(Bg + (size_t)r1 * D_ + (d0) + sw), \
        (__attribute__((address_space(3))) void*)&Bs[buf][wv * 512], 16, 0, 0); \
    __builtin_amdgcn_global_load_lds( \
        (const __attribute__((address_space(1))) void*)(Bg + (size_t)(r1 + 32) * D_ + (d0) + sw), \
        (__attribute__((address_space(3))) void*)&Bs[buf][2048 + wv * 512], 16, 0, 0); \
  } while (0)

#define MFMA(a, b, c) __builtin_amdgcn_mfma_f32_16x16x32_bf16((a), (b), (c), 0, 0, 0)

#define K_ITER(KT, BUF, PREFETCH, VMSTR, LAST) do { \
    const int rowa = wr * 32 + fr, rowb = wc * 32 + fr; \
    bf16x8_t af0 = *reinterpret_cast<const bf16x8_t*>(&As[BUF][SWZ_ELEM(rowa, fq)]); \
    bf16x8_t af1 = *reinterpret_cast<const bf16x8_t*>(&As[BUF][SWZ_ELEM(rowa, 4 + fq)]); \
    bf16x8_t af2 = *reinterpret_cast<const bf16x8_t*>(&As[BUF][SWZ_ELEM(rowa + 16, fq)]); \
    bf16x8_t af3 = *reinterpret_cast<const bf16x8_t*>(&As[BUF][SWZ_ELEM(rowa + 16, 4 + fq)]); \
    bf16x8_t bf0 = *reinterpret_cast<const bf16x8_t*>(&Bs[BUF][SWZ_ELEM(rowb, fq)]); \
    bf16x8_t bf1 = *reinterpret_cast<const bf16x8_t*>(&Bs[BUF][SWZ_ELEM(rowb, 4 + fq)]); \
    bf16x8_t bf2 = *reinterpret_cast<const bf16x8_t*>(&Bs[BUF][SWZ_ELEM(rowb + 16, fq)]); \
    bf16x8_t bf3 = *reinterpret_cast<const bf16x8_t*>(&Bs[BUF][SWZ_ELEM(rowb + 16, 4 + fq)]); \
    asm volatile("s_waitcnt lgkmcnt(0)" ::: "memory"); \
    __builtin_amdgcn_sched_barrier(0); \
    __builtin_amdgcn_s_barrier(); \
    if (PREFETCH) STAGE_AB(BUF, ((KT) + 3) * 64); \
    acc[0][0] = MFMA(af0, bf0, acc[0][0]); \
    acc[0][1] = MFMA(af0, bf2, acc[0][1]); \
    acc[1][0] = MFMA(af2, bf0, acc[1][0]); \
    acc[1][1] = MFMA(af2, bf2, acc[1][1]); \
    acc[0][0] = MFMA(af1, bf1, acc[0][0]); \
    acc[0][1] = MFMA(af1, bf3, acc[0][1]); \
    acc[1][0] = MFMA(af3, bf1, acc[1][0]); \
    acc[1][1] = MFMA(af3, bf3, acc[1][1]); \
    if (!(LAST)) { \
      asm volatile("s_waitcnt " VMSTR ::: "memory"); \
      __builtin_amdgcn_sched_barrier(0); \
      __builtin_amdgcn_s_barrier(); \
    } \
  } while (0)

  // ---- prologue: tiles 0,1,2 in flight; wait tile 0; barrier ----
  STAGE_AB(0, 0);
  STAGE_AB(1, 64);
  STAGE_AB(2, 128);
  asm volatile("s_waitcnt vmcnt(8)" ::: "memory");   // tile 0's 4 loads landed
  __builtin_amdgcn_sched_barrier(0);
  __builtin_amdgcn_s_barrier();

  K_ITER(0, 0, 1, "vmcnt(8)", 0);   // stages tile 3 -> buf0
  K_ITER(1, 1, 1, "vmcnt(8)", 0);   // tile 4 -> buf1
  K_ITER(2, 2, 1, "vmcnt(8)", 0);   // tile 5 -> buf2
  K_ITER(3, 0, 1, "vmcnt(8)", 0);   // tile 6 -> buf0
  K_ITER(4, 1, 1, "vmcnt(8)", 0);   // tile 7 -> buf1
  K_ITER(5, 2, 0, "vmcnt(4)", 0);   // outstanding: t6,t7 -> wait t6
  K_ITER(6, 0, 0, "vmcnt(0)", 0);   // wait t7
  K_ITER(7, 1, 0, "vmcnt(0)", 1);

#undef K_ITER
#undef MFMA
#undef STAGE_AB

  // ---- epilogue: coalesced bf16 store to ws2[p][b][e] (+bias) ----
  const int q4 = fq * 4;
  #pragma unroll
  for (int jj = 0; jj < 2; ++jj) {
    const int e  = e0t + wc * 32 + jj * 16 + fr;
    const float bv = bias[p * E_ + e];
    #pragma unroll
    for (int ii = 0; ii < 2; ++ii) {
      const int r0 = b0 + wr * 32 + ii * 16 + q4;
      #pragma unroll
      for (int rg = 0; rg < 4; ++rg) {
        ws2[((size_t)p * B_ + (r0 + rg)) * E_ + e] = f2bf(acc[ii][jj][rg] + bv);
      }
    }
  }
}

// ---------------------------------------------------------------------------
// Pass 3: ws2[p][b][e] bf16 -> out[b][e][p] f32; padded-LDS 64x64 transpose,
// coalesced read (e-contiguous bf16) and write (p-contiguous float4).
// Grid: (b=256, pblk=2, eblk=2).
// ---------------------------------------------------------------------------
__global__ __launch_bounds__(256) void out_transpose_kernel(
    const u16* __restrict__ ws2, float* __restrict__ out) {
  __shared__ float tile[64][65];

  const int b  = blockIdx.x;
  const int p0 = blockIdx.y * 64;
  const int e0 = blockIdx.z * 64;
  const int t  = threadIdx.x;

  const u16* s = ws2 + ((size_t)p0 * B_ + b) * E_ + e0;   // p-row stride B_*E_

  {
    const int lr = t >> 4;          // p-local row 0..15
    const int lc = (t & 15) * 4;    // e-local col
    #pragma unroll
    for (int it = 0; it < 4; ++it) {
      const int r = lr + it * 16;
      const u16x4_t v = *reinterpret_cast<const u16x4_t*>(s + (size_t)r * (B_ * E_) + lc);
      tile[r][lc + 0] = bf2f(v[0]); tile[r][lc + 1] = bf2f(v[1]);
      tile[r][lc + 2] = bf2f(v[2]); tile[r][lc + 3] = bf2f(v[3]);
    }
  }
  __syncthreads();

  {
    const int c  = t >> 4;          // e-local col base
    const int wd = (t & 15) * 4;    // p-local row chunk
    #pragma unroll
    for (int it = 0; it < 4; ++it) {
      const int cc = c + it * 16;
      float4 v;
      v.x = tile[wd + 0][cc]; v.y = tile[wd + 1][cc];
      v.z = tile[wd + 2][cc]; v.w = tile[wd + 3][cc];
      *reinterpret_cast<float4*>(out + ((size_t)b * E_ + e0 + cc) * P_ + p0 + wd) = v;
    }
  }
}

// ---------------------------------------------------------------------------
// Fallback (only if workspace is too small): naive but correct.
// ---------------------------------------------------------------------------
__global__ __launch_bounds__(256) void naive_kernel(
    const float* __restrict__ x, const float* __restrict__ W,
    const float* __restrict__ bias, float* __restrict__ out) {
  const size_t idx = (size_t)blockIdx.x * 256 + threadIdx.x;
  const int p = (int)(idx & 127);
  const int e = (int)((idx >> 7) & 127);
  const int b = (int)(idx >> 14);
  float acc = bias[p * E_ + e];
  const float* xp = x + (size_t)b * D_ * P_ + p;
  const float* wp = W + (size_t)p * D_ * E_ + e;
  for (int d = 0; d < D_; ++d) acc += xp[(size_t)d * P_] * wp[(size_t)d * E_];
  out[idx] = acc;
}

extern "C" void kernel_launch(void* const* d_in, const int* in_sizes, int n_in,
                              void* d_out, int out_size, void* d_ws, size_t ws_size,
                              hipStream_t stream) {
  (void)in_sizes; (void)n_in; (void)out_size;
  const float* x    = (const float*)d_in[0];   // [B,D,P] f32
  const float* W    = (const float*)d_in[1];   // [P,D,E] f32
  const float* bias = (const float*)d_in[2];   // [P,E]   f32
  float* out = (float*)d_out;                  // [B,E,P] f32

  const size_t xT_bytes  = (size_t)P_ * B_ * D_ * 2;   // 32 MiB
  const size_t Wt_bytes  = (size_t)P_ * E_ * D_ * 2;   // 16 MiB
  const size_t ws2_bytes = (size_t)P_ * B_ * E_ * 2;   // 8 MiB

  if (ws_size < xT_bytes + Wt_bytes + ws2_bytes) {
    naive_kernel<<<dim3((B_ * E_ * P_) / 256), 256, 0, stream>>>(x, W, bias, out);
    return;
  }

  u16* xT  = (u16*)d_ws;                                    // [P][B][D] bf16
  u16* Wt  = (u16*)((char*)d_ws + xT_bytes);                // [P][E][D] bf16
  u16* ws2 = (u16*)((char*)d_ws + xT_bytes + Wt_bytes);     // [P][B][E] bf16

  transpose_both_kernel<<<dim3(B_ + P_, 8, 2), 256, 0, stream>>>(x, W, xT, Wt);
  gemm_kernel<<<dim3(1024), 256, 0, stream>>>(xT, Wt, bias, ws2);
  out_transpose_kernel<<<dim3(B_, 2, 2), 256, 0, stream>>>(ws2, out);
}

// Round 10
// 44.895 us; speedup vs baseline: 1.0636x; 1.0636x over previous
//
#include <hip/hip_runtime.h>
#include <cstdint>
#include <cstddef>

// Problem constants
#define B_ 256
#define D_ 512
#define P_ 128
#define E_ 128

typedef unsigned short u16;
typedef unsigned int   u32;
typedef __bf16  bf16x8_t __attribute__((ext_vector_type(8)));
typedef float   f32x4_t  __attribute__((ext_vector_type(4)));
typedef u16     u16x4_t  __attribute__((ext_vector_type(4)));
typedef u16     u16x8_t  __attribute__((ext_vector_type(8)));

__device__ __forceinline__ u16 f2bf(float f) {
  union { float f; unsigned int u; } c; c.f = f;
  unsigned int u = c.u;
  unsigned int r = (u + 0x7FFFu + ((u >> 16) & 1u)) >> 16;
  return (u16)r;
}
__device__ __forceinline__ float bf2f(u16 v) {
  union { unsigned int u; float f; } c; c.u = (unsigned int)v << 16;
  return c.f;
}

// ---------------------------------------------------------------------------
// Pass 1: transpose + convert f32 -> bf16, CONTIGUOUS-WRITE version.
// Block = 32 columns x all 512 d. Phase-1: coalesced float4 row reads into
// LDS [32][516] f32 (pad 4 keeps 16B alignment; <=4-way write conflicts,
// effectively-free b128 reads). Phase-2: each dst row (c) written as a
// CONTIGUOUS 1KB stream (8 x 128B runs, sequential) — replaces r9's 128B@
// 256KB-stride scatter that held the transpose at 2.4 TB/s.
// bid<1024: x [b][512d][128p] -> xT[p][b][d]; else W -> Wt[p][e][d].
// ---------------------------------------------------------------------------
__global__ __launch_bounds__(256) void transpose_cvt2_kernel(
    const float* __restrict__ x, const float* __restrict__ W,
    u16* __restrict__ xT, u16* __restrict__ Wt) {
  __shared__ float tile[32][516];

  const int bid  = blockIdx.x;
  const bool isX = (bid < 1024);
  const int o    = isX ? (bid >> 2) : ((bid - 1024) >> 2);
  const int c0   = (bid & 3) * 32;
  const float* src = isX ? x : W;
  u16* dst = isX ? xT : Wt;
  const size_t rs = isX ? (size_t)(B_ * D_) : (size_t)D_;   // dst row stride (c)
  const size_t os = isX ? (size_t)D_ : (size_t)(E_ * D_);   // dst outer stride (o)

  const int t = threadIdx.x;

  // phase 1: 16 passes, each thread reads float4 (4 cols) of one d-row
  {
    const float* s = src + (size_t)o * (D_ * 128) + c0 + (t & 7) * 4;
    const int cl = (t & 7) * 4;
    #pragma unroll
    for (int j = 0; j < 16; ++j) {
      const int d = (t >> 3) + 32 * j;
      const float4 v = *reinterpret_cast<const float4*>(s + (size_t)d * 128);
      tile[cl + 0][d] = v.x; tile[cl + 1][d] = v.y;
      tile[cl + 2][d] = v.z; tile[cl + 3][d] = v.w;
    }
  }
  __syncthreads();

  // phase 2: thread (c = t>>3, m = t&7) writes 16B chunks; per wave each
  // dst row gets 128B runs, rows filled contiguously across its.
  {
    const int c = t >> 3;
    const int m = t & 7;
    u16* drow = dst + (size_t)(c0 + c) * rs + (size_t)o * os;
    #pragma unroll
    for (int it = 0; it < 8; ++it) {
      const int db = m * 8 + it * 64;
      u16x8_t pk;
      #pragma unroll
      for (int k = 0; k < 8; ++k) pk[k] = f2bf(tile[c][db + k]);
      *reinterpret_cast<u16x8_t*>(drow + db) = pk;
    }
  }
}

// ---------------------------------------------------------------------------
// Pass 2: per-p bf16 TN GEMM, 128(b) x 128(e) x BK=64 tile — A and B each
// read ONCE per p (halves gemm global reads vs the 64x64 tiling: 128->64MiB).
// 512 threads / 8 waves (2b x 4e), TRIPLE-buffered LDS (96KB), depth-3
// counted-vmcnt pipeline (r9-verified schedule: 4 gload_lds per thread per
// tile -> vmcnt(8)/(4)/(0) identical). Grid = 256 WGs = 1 WG/CU, 2 waves/EU;
// XCD-swizzled p (16 p per XCD -> Wt/xT slices L2-local).
// Epilogue: coalesced bf16 store to ws2[p][b][e] (+bias).
// ---------------------------------------------------------------------------

// swizzled elem index of 16B chunk g (0..7) in row `row` of a [row][64]-u16 tile
#define SWZ_ELEM(row, g) (((row) << 6) + ((((g) ^ ((row) & 7))) << 3))

__global__ __launch_bounds__(512, 2) void gemm_kernel(
    const u16* __restrict__ xT, const u16* __restrict__ Wt,
    const float* __restrict__ bias, u16* __restrict__ ws2) {
  __shared__ __attribute__((aligned(16))) u16 As[3][128 * 64];
  __shared__ __attribute__((aligned(16))) u16 Bs[3][128 * 64];

  const int wg  = blockIdx.x;          // 0..255
  const int xcd = wg & 7;
  const int i   = wg >> 3;             // 0..31
  const int p   = xcd * 16 + (i & 15);
  const int b0  = (i >> 4) * 128;      // 0 or 128

  const int t    = threadIdx.x;
  const int lane = t & 63;
  const int wv   = t >> 6;             // wave 0..7
  const int wr   = wv >> 2;            // b half (0,1)
  const int wc   = wv & 3;             // e quarter (0..3)

  const u16* Ag = xT + (size_t)p * (B_ * D_) + (size_t)b0 * D_;
  const u16* Bg = Wt + (size_t)p * (E_ * D_);

  // staging: thread t stages 16B chunks t and t+512 of each 128x64 tile.
  // LDS dest linear (wave base + lane*16); global source pre-XOR-swizzled.
  const int r1 = t >> 3;                           // row of chunk t (0..63)
  const int sw = (((t & 7) ^ (r1 & 7)) << 3);      // swizzled elem offset

  const int fr = lane & 15;
  const int fq = lane >> 4;

  f32x4_t acc[4][2] = {};

#define GLOAD(gp, lp) __builtin_amdgcn_global_load_lds( \
    (const __attribute__((address_space(1))) void*)(gp), \
    (__attribute__((address_space(3))) void*)(lp), 16, 0, 0)

#define STAGE_AB(buf, d0) do { \
    GLOAD(Ag + (size_t)r1 * D_ + (d0) + sw,        &As[buf][wv * 512]); \
    GLOAD(Ag + (size_t)(r1 + 64) * D_ + (d0) + sw, &As[buf][4096 + wv * 512]); \
    GLOAD(Bg + (size_t)r1 * D_ + (d0) + sw,        &Bs[buf][wv * 512]); \
    GLOAD(Bg + (size_t)(r1 + 64) * D_ + (d0) + sw, &Bs[buf][4096 + wv * 512]); \
  } while (0)

#define MFMA(a, b, c) __builtin_amdgcn_mfma_f32_16x16x32_bf16((a), (b), (c), 0, 0, 0)

#define K_ITER(KT, BUF, PREFETCH, VMSTR, LAST) do { \
    bf16x8_t af[4][2], bfr[2][2]; \
    _Pragma("unroll") \
    for (int ii = 0; ii < 4; ++ii) { \
      const int rowa = wr * 64 + ii * 16 + fr; \
      af[ii][0] = *reinterpret_cast<const bf16x8_t*>(&As[BUF][SWZ_ELEM(rowa, fq)]); \
      af[ii][1] = *reinterpret_cast<const bf16x8_t*>(&As[BUF][SWZ_ELEM(rowa, 4 + fq)]); \
    } \
    _Pragma("unroll") \
    for (int jj = 0; jj < 2; ++jj) { \
      const int rowb = wc * 32 + jj * 16 + fr; \
      bfr[jj][0] = *reinterpret_cast<const bf16x8_t*>(&Bs[BUF][SWZ_ELEM(rowb, fq)]); \
      bfr[jj][1] = *reinterpret_cast<const bf16x8_t*>(&Bs[BUF][SWZ_ELEM(rowb, 4 + fq)]); \
    } \
    asm volatile("s_waitcnt lgkmcnt(0)" ::: "memory"); \
    __builtin_amdgcn_sched_barrier(0); \
    __builtin_amdgcn_s_barrier(); \
    if (PREFETCH) STAGE_AB(BUF, ((KT) + 3) * 64); \
    _Pragma("unroll") \
    for (int kh = 0; kh < 2; ++kh) \
      _Pragma("unroll") \
      for (int ii = 0; ii < 4; ++ii) \
        _Pragma("unroll") \
        for (int jj = 0; jj < 2; ++jj) \
          acc[ii][jj] = MFMA(af[ii][kh], bfr[jj][kh], acc[ii][jj]); \
    if (!(LAST)) { \
      asm volatile("s_waitcnt " VMSTR ::: "memory"); \
      __builtin_amdgcn_sched_barrier(0); \
      __builtin_amdgcn_s_barrier(); \
    } \
  } while (0)

  // ---- prologue: tiles 0,1,2 in flight; wait tile 0; barrier ----
  STAGE_AB(0, 0);
  STAGE_AB(1, 64);
  STAGE_AB(2, 128);
  asm volatile("s_waitcnt vmcnt(8)" ::: "memory");   // tile 0's 4 loads landed
  __builtin_amdgcn_sched_barrier(0);
  __builtin_amdgcn_s_barrier();

  K_ITER(0, 0, 1, "vmcnt(8)", 0);   // stages tile 3 -> buf0
  K_ITER(1, 1, 1, "vmcnt(8)", 0);   // tile 4 -> buf1
  K_ITER(2, 2, 1, "vmcnt(8)", 0);   // tile 5 -> buf2
  K_ITER(3, 0, 1, "vmcnt(8)", 0);   // tile 6 -> buf0
  K_ITER(4, 1, 1, "vmcnt(8)", 0);   // tile 7 -> buf1
  K_ITER(5, 2, 0, "vmcnt(4)", 0);   // wait tile 6
  K_ITER(6, 0, 0, "vmcnt(0)", 0);   // wait tile 7
  K_ITER(7, 1, 0, "vmcnt(0)", 1);

#undef K_ITER
#undef MFMA
#undef STAGE_AB
#undef GLOAD

  // ---- epilogue: coalesced bf16 store to ws2[p][b][e] (+bias) ----
  const int q4 = fq * 4;
  #pragma unroll
  for (int jj = 0; jj < 2; ++jj) {
    const int e  = wc * 32 + jj * 16 + fr;
    const float bv = bias[p * E_ + e];
    #pragma unroll
    for (int ii = 0; ii < 4; ++ii) {
      const int r0 = b0 + wr * 64 + ii * 16 + q4;
      #pragma unroll
      for (int rg = 0; rg < 4; ++rg) {
        ws2[((size_t)p * B_ + (r0 + rg)) * E_ + e] = f2bf(acc[ii][jj][rg] + bv);
      }
    }
  }
}

// ---------------------------------------------------------------------------
// Pass 3: ws2[p][b][e] bf16 -> out[b][e][p] f32; padded-LDS 64x64 transpose,
// coalesced read (e-contiguous bf16) and write (p-contiguous float4).
// Grid: (b=256, pblk=2, eblk=2).
// ---------------------------------------------------------------------------
__global__ __launch_bounds__(256) void out_transpose_kernel(
    const u16* __restrict__ ws2, float* __restrict__ out) {
  __shared__ float tile[64][65];

  const int b  = blockIdx.x;
  const int p0 = blockIdx.y * 64;
  const int e0 = blockIdx.z * 64;
  const int t  = threadIdx.x;

  const u16* s = ws2 + ((size_t)p0 * B_ + b) * E_ + e0;   // p-row stride B_*E_

  {
    const int lr = t >> 4;          // p-local row 0..15
    const int lc = (t & 15) * 4;    // e-local col
    #pragma unroll
    for (int it = 0; it < 4; ++it) {
      const int r = lr + it * 16;
      const u16x4_t v = *reinterpret_cast<const u16x4_t*>(s + (size_t)r * (B_ * E_) + lc);
      tile[r][lc + 0] = bf2f(v[0]); tile[r][lc + 1] = bf2f(v[1]);
      tile[r][lc + 2] = bf2f(v[2]); tile[r][lc + 3] = bf2f(v[3]);
    }
  }
  __syncthreads();

  {
    const int c  = t >> 4;          // e-local col base
    const int wd = (t & 15) * 4;    // p-local row chunk
    #pragma unroll
    for (int it = 0; it < 4; ++it) {
      const int cc = c + it * 16;
      float4 v;
      v.x = tile[wd + 0][cc]; v.y = tile[wd + 1][cc];
      v.z = tile[wd + 2][cc]; v.w = tile[wd + 3][cc];
      *reinterpret_cast<float4*>(out + ((size_t)b * E_ + e0 + cc) * P_ + p0 + wd) = v;
    }
  }
}

// ---------------------------------------------------------------------------
// Fallback (only if workspace is too small): naive but correct.
// ---------------------------------------------------------------------------
__global__ __launch_bounds__(256) void naive_kernel(
    const float* __restrict__ x, const float* __restrict__ W,
    const float* __restrict__ bias, float* __restrict__ out) {
  const size_t idx = (size_t)blockIdx.x * 256 + threadIdx.x;
  const int p = (int)(idx & 127);
  const int e = (int)((idx >> 7) & 127);
  const int b = (int)(idx >> 14);
  float acc = bias[p * E_ + e];
  const float* xp = x + (size_t)b * D_ * P_ + p;
  const float* wp = W + (size_t)p * D_ * E_ + e;
  for (int d = 0; d < D_; ++d) acc += xp[(size_t)d * P_] * wp[(size_t)d * E_];
  out[idx] = acc;
}

extern "C" void kernel_launch(void* const* d_in, const int* in_sizes, int n_in,
                              void* d_out, int out_size, void* d_ws, size_t ws_size,
                              hipStream_t stream) {
  (void)in_sizes; (void)n_in; (void)out_size;
  const float* x    = (const float*)d_in[0];   // [B,D,P] f32
  const float* W    = (const float*)d_in[1];   // [P,D,E] f32
  const float* bias = (const float*)d_in[2];   // [P,E]   f32
  float* out = (float*)d_out;                  // [B,E,P] f32

  const size_t xT_bytes  = (size_t)P_ * B_ * D_ * 2;   // 32 MiB
  const size_t Wt_bytes  = (size_t)P_ * E_ * D_ * 2;   // 16 MiB
  const size_t ws2_bytes = (size_t)P_ * B_ * E_ * 2;   // 8 MiB

  if (ws_size < xT_bytes + Wt_bytes + ws2_bytes) {
    naive_kernel<<<dim3((B_ * E_ * P_) / 256), 256, 0, stream>>>(x, W, bias, out);
    return;
  }

  u16* xT  = (u16*)d_ws;                                    // [P][B][D] bf16
  u16* Wt  = (u16*)((char*)d_ws + xT_bytes);                // [P][E][D] bf16
  u16* ws2 = (u16*)((char*)d_ws + xT_bytes + Wt_bytes);     // [P][B][E] bf16

  // x: 1024 blocks (256 o x 4 col-blocks); W: 512 blocks (128 o x 4)
  transpose_cvt2_kernel<<<dim3(1536), 256, 0, stream>>>(x, W, xT, Wt);
  gemm_kernel<<<dim3(256), 512, 0, stream>>>(xT, Wt, bias, ws2);
  out_transpose_kernel<<<dim3(B_, 2, 2), 256, 0, stream>>>(ws2, out);
}